// Round 6
// baseline (1023.664 us; speedup 1.0000x reference)
//
#include <hip/hip_runtime.h>

#define D_MODEL 1024
#define NH 16
#define HD 64
#define KRET 32
#define BANK 131072
#define BB 8
#define TT 2048
#define MTOK 16384
#define EPSN 1e-12f

typedef __attribute__((ext_vector_type(8))) short bf16x8;
typedef __attribute__((ext_vector_type(8))) unsigned short u16x8;
typedef __attribute__((ext_vector_type(4))) float f32x4;

__device__ __forceinline__ unsigned short f2bf(float f) {
  unsigned int u = __float_as_uint(f);
  u += 0x7fffu + ((u >> 16) & 1u);
  return (unsigned short)(u >> 16);
}
__device__ __forceinline__ float bf2f(unsigned short h) {
  return __uint_as_float(((unsigned int)h) << 16);
}

__device__ __forceinline__ void gload16(const void* g, void* l) {
  __builtin_amdgcn_global_load_lds(
      (const __attribute__((address_space(1))) unsigned int*)g,
      (__attribute__((address_space(3))) unsigned int*)l, 16, 0, 0);
}

// ---------------- fused prep: conv_mean (blocks 0..511) + transW (blocks 512..1535) ----------------
__global__ __launch_bounds__(256) void k_prep(const float* __restrict__ x,
                                              unsigned short* __restrict__ xb,
                                              float* __restrict__ part,
                                              const float* W0, const float* W1,
                                              const float* W2, const float* W3,
                                              unsigned short* T0, unsigned short* T1,
                                              unsigned short* T2, unsigned short* T3) {
  __shared__ float tile[64][65];
  int id = blockIdx.x, tid = threadIdx.x;
  if (id < 512) {
    int ch = id & 63, b = id >> 6;
    const float4* xp = (const float4*)(x + ((size_t)b * TT + ch * 32) * D_MODEL);
    ushort4* xo = (ushort4*)(xb + ((size_t)b * TT + ch * 32) * D_MODEL);
    float4 acc = {0.f, 0.f, 0.f, 0.f};
#pragma unroll 4
    for (int t = 0; t < 32; t++) {
      float4 v = xp[t * 256 + tid];
      acc.x += v.x; acc.y += v.y; acc.z += v.z; acc.w += v.w;
      ushort4 o;
      o.x = f2bf(v.x); o.y = f2bf(v.y); o.z = f2bf(v.z); o.w = f2bf(v.w);
      xo[t * 256 + tid] = o;
    }
    ((float4*)part)[((size_t)b * 64 + ch) * 256 + tid] = acc;
  } else {
    int wid = id - 512;
    int nx = wid & 15, ny = (wid >> 4) & 15, nz = wid >> 8;
    const float* W; unsigned short* T;
    switch (nz) {
      case 0: W = W0; T = T0; break;
      case 1: W = W1; T = T1; break;
      case 2: W = W2; T = T2; break;
      default: W = W3; T = T3; break;
    }
    int k0 = ny * 64, n0 = nx * 64;
#pragma unroll
    for (int i = 0; i < 16; i++) {
      int idx = tid + i * 256; int r = idx >> 6, c = idx & 63;
      tile[r][c] = W[(size_t)(k0 + r) * D_MODEL + n0 + c];
    }
    __syncthreads();
#pragma unroll
    for (int i = 0; i < 16; i++) {
      int idx = tid + i * 256; int r = idx >> 6, c = idx & 63;
      T[(size_t)(n0 + r) * D_MODEL + k0 + c] = f2bf(tile[c][r]);
    }
  }
}

// ---------------- finish mean (64 partials) + normalize q ----------------
__global__ __launch_bounds__(256) void k_qnorm(const float* __restrict__ part,
                                               float* __restrict__ qn) {
  int b = blockIdx.x; int tid = threadIdx.x;
  __shared__ float red[4];
  const float4* pp = (const float4*)part + (size_t)b * 64 * 256 + tid;
  float4 a = {0.f, 0.f, 0.f, 0.f};
#pragma unroll 8
  for (int p = 0; p < 64; p++) {
    float4 v = pp[(size_t)p * 256];
    a.x += v.x; a.y += v.y; a.z += v.z; a.w += v.w;
  }
  const float sc = 1.f / (float)TT;
  a.x *= sc; a.y *= sc; a.z *= sc; a.w *= sc;
  float ss = a.x * a.x + a.y * a.y + a.z * a.z + a.w * a.w;
#pragma unroll
  for (int m = 32; m >= 1; m >>= 1) ss += __shfl_xor(ss, m);
  if ((tid & 63) == 0) red[tid >> 6] = ss;
  __syncthreads();
  float tot = red[0] + red[1] + red[2] + red[3];
  float inv = 1.f / fmaxf(sqrtf(tot), EPSN);
  float4 o = {a.x * inv, a.y * inv, a.z * inv, a.w * inv};
  ((float4*)qn)[(size_t)b * 256 + tid] = o;
}

// ---------------- cosine sims: one wave per 4 key rows ----------------
__global__ __launch_bounds__(256) void k_sims(const float* __restrict__ mk,
                                              const float* __restrict__ qn,
                                              float* __restrict__ sims) {
  int wave = threadIdx.x >> 6, lane = threadIdx.x & 63;
  int row0 = (blockIdx.x * 4 + wave) * 4;
  float4 kv[4][4];
#pragma unroll
  for (int r = 0; r < 4; r++) {
    const float4* kr = (const float4*)(mk + (size_t)(row0 + r) * D_MODEL);
#pragma unroll
    for (int i = 0; i < 4; i++) kv[r][i] = kr[lane + 64 * i];
  }
  float ss[4] = {0.f, 0.f, 0.f, 0.f};
#pragma unroll
  for (int r = 0; r < 4; r++)
#pragma unroll
    for (int i = 0; i < 4; i++)
      ss[r] += kv[r][i].x * kv[r][i].x + kv[r][i].y * kv[r][i].y +
               kv[r][i].z * kv[r][i].z + kv[r][i].w * kv[r][i].w;
  float dots[8][4];
#pragma unroll
  for (int b = 0; b < 8; b++)
#pragma unroll
    for (int r = 0; r < 4; r++) dots[b][r] = 0.f;
#pragma unroll
  for (int b = 0; b < 8; b++) {
    const float4* qb = (const float4*)(qn + (size_t)b * D_MODEL);
#pragma unroll
    for (int i = 0; i < 4; i++) {
      float4 q4 = qb[lane + 64 * i];
#pragma unroll
      for (int r = 0; r < 4; r++)
        dots[b][r] += kv[r][i].x * q4.x + kv[r][i].y * q4.y +
                      kv[r][i].z * q4.z + kv[r][i].w * q4.w;
    }
  }
#pragma unroll
  for (int m = 32; m >= 1; m >>= 1) {
#pragma unroll
    for (int r = 0; r < 4; r++) ss[r] += __shfl_xor(ss[r], m);
#pragma unroll
    for (int b = 0; b < 8; b++)
#pragma unroll
      for (int r = 0; r < 4; r++) dots[b][r] += __shfl_xor(dots[b][r], m);
  }
  if (lane == 0) {
#pragma unroll
    for (int r = 0; r < 4; r++) {
      float inv = 1.f / fmaxf(sqrtf(ss[r]), EPSN);
#pragma unroll
      for (int b = 0; b < 8; b++)
        sims[(size_t)b * BANK + row0 + r] = dots[b][r] * inv;
    }
  }
}

// ---------------- two-stage exact top-32 ----------------
__global__ __launch_bounds__(256) void k_topk_local(const float* __restrict__ sims,
                                                    float* __restrict__ cval,
                                                    int* __restrict__ cidx) {
  int b = blockIdx.y, chunk = blockIdx.x;
  int tid = threadIdx.x, wave = tid >> 6, lane = tid & 63;
  const float* sb = sims + (size_t)b * BANK + chunk * 2048;
  float v[8]; int gi[8];
#pragma unroll
  for (int j = 0; j < 8; j++) {
    int loc = j * 256 + tid;
    v[j] = sb[loc];
    gi[j] = chunk * 2048 + loc;
  }
  __shared__ float wv[4]; __shared__ int wi[4];
  __shared__ int bcast;
  for (int it = 0; it < KRET; ++it) {
    float best = -1e30f; int besti = 1 << 30;
#pragma unroll
    for (int j = 0; j < 8; j++)
      if (v[j] > best || (v[j] == best && gi[j] < besti)) { best = v[j]; besti = gi[j]; }
#pragma unroll
    for (int m = 32; m >= 1; m >>= 1) {
      float ov = __shfl_xor(best, m); int oi = __shfl_xor(besti, m);
      if (ov > best || (ov == best && oi < besti)) { best = ov; besti = oi; }
    }
    if (lane == 0) { wv[wave] = best; wi[wave] = besti; }
    __syncthreads();
    if (tid == 0) {
      float fb = wv[0]; int fi = wi[0];
      for (int w = 1; w < 4; w++)
        if (wv[w] > fb || (wv[w] == fb && wi[w] < fi)) { fb = wv[w]; fi = wi[w]; }
      bcast = fi;
      cval[((size_t)b * 64 + chunk) * KRET + it] = fb;
      cidx[((size_t)b * 64 + chunk) * KRET + it] = fi;
    }
    __syncthreads();
    int w = bcast;
#pragma unroll
    for (int j = 0; j < 8; j++)
      if (gi[j] == w) v[j] = -1e30f;
  }
}

__global__ __launch_bounds__(256) void k_topk_merge(const float* __restrict__ cval,
                                                    const int* __restrict__ cidx,
                                                    int* __restrict__ idx) {
  int b = blockIdx.x;
  int tid = threadIdx.x, wave = tid >> 6, lane = tid & 63;
  const float* cv = cval + (size_t)b * 2048;
  const int* ci = cidx + (size_t)b * 2048;
  float v[8]; int gi[8];
#pragma unroll
  for (int j = 0; j < 8; j++) {
    int loc = j * 256 + tid;
    v[j] = cv[loc];
    gi[j] = ci[loc];
  }
  __shared__ float wv[4]; __shared__ int wi[4];
  __shared__ int bcast;
  for (int it = 0; it < KRET; ++it) {
    float best = -1e30f; int besti = 1 << 30;
#pragma unroll
    for (int j = 0; j < 8; j++)
      if (v[j] > best || (v[j] == best && gi[j] < besti)) { best = v[j]; besti = gi[j]; }
#pragma unroll
    for (int m = 32; m >= 1; m >>= 1) {
      float ov = __shfl_xor(best, m); int oi = __shfl_xor(besti, m);
      if (ov > best || (ov == best && oi < besti)) { best = ov; besti = oi; }
    }
    if (lane == 0) { wv[wave] = best; wi[wave] = besti; }
    __syncthreads();
    if (tid == 0) {
      float fb = wv[0]; int fi = wi[0];
      for (int w = 1; w < 4; w++)
        if (wv[w] > fb || (wv[w] == fb && wi[w] < fi)) { fb = wv[w]; fi = wi[w]; }
      bcast = fi;
      idx[b * KRET + it] = fi;
    }
    __syncthreads();
    int w = bcast;
#pragma unroll
    for (int j = 0; j < 8; j++)
      if (gi[j] == w) v[j] = -1e30f;
  }
}

// ---------------- KV projection with fused gather: A rows = mv[idx[.]] ----------------
__global__ __launch_bounds__(256) void k_kvgemm(const float* __restrict__ mv,
                                                const int* __restrict__ idx_g,
                                                const unsigned short* __restrict__ Bt,
                                                float* __restrict__ Kout,
                                                float* __restrict__ Vout) {
  __shared__ __align__(16) unsigned short As[128 * 32];
  __shared__ __align__(16) unsigned short Bs[128 * 32];
  __shared__ int idxs[128];
  const int tid = threadIdx.x;
  const int wave = tid >> 6, lane = tid & 63;
  const int bm = blockIdx.x * 128, bn = blockIdx.y * 128;
  const int wm = (wave >> 1) * 64, wn = (wave & 1) * 64;
  const int frow = lane & 15, kg = lane >> 4;
  const int K = 1024;

  if (tid < 128) idxs[tid] = idx_g[bm + tid];
  __syncthreads();

  f32x4 acc[4][4] = {};

  const int row0 = tid >> 2, col0 = (tid & 3) * 8;
  const int row1 = row0 + 64;
  const int g0 = tid * 8;
  const int g1 = 2048 + tid * 8;
  const unsigned short* b0 = Bt + (size_t)(bn + (g0 >> 5)) * K + (g0 & 31);
  const unsigned short* b1 = Bt + (size_t)(bn + (g1 >> 5)) * K + (g1 & 31);
  unsigned short* lB0 = &Bs[wave * 512];
  unsigned short* lB1 = &Bs[2048 + wave * 512];
  const float* src0 = mv + (size_t)idxs[row0] * D_MODEL + col0;
  const float* src1 = mv + (size_t)idxs[row1] * D_MODEL + col0;

  for (int k0 = 0; k0 < K; k0 += 32) {
    gload16(b0 + k0, lB0);
    gload16(b1 + k0, lB1);
    float4 u0 = *(const float4*)(src0 + k0);
    float4 w0 = *(const float4*)(src0 + k0 + 4);
    float4 u1 = *(const float4*)(src1 + k0);
    float4 w1 = *(const float4*)(src1 + k0 + 4);
    u16x8 p0, p1;
    p0[0] = f2bf(u0.x); p0[1] = f2bf(u0.y); p0[2] = f2bf(u0.z); p0[3] = f2bf(u0.w);
    p0[4] = f2bf(w0.x); p0[5] = f2bf(w0.y); p0[6] = f2bf(w0.z); p0[7] = f2bf(w0.w);
    p1[0] = f2bf(u1.x); p1[1] = f2bf(u1.y); p1[2] = f2bf(u1.z); p1[3] = f2bf(u1.w);
    p1[4] = f2bf(w1.x); p1[5] = f2bf(w1.y); p1[6] = f2bf(w1.z); p1[7] = f2bf(w1.w);
    *(u16x8*)&As[row0 * 32 + col0] = p0;
    *(u16x8*)&As[row1 * 32 + col0] = p1;
    __syncthreads();
    bf16x8 fa[4], fb[4];
#pragma unroll
    for (int i = 0; i < 4; i++)
      fa[i] = *(const bf16x8*)&As[(wm + i * 16 + frow) * 32 + kg * 8];
#pragma unroll
    for (int i = 0; i < 4; i++)
      fb[i] = *(const bf16x8*)&Bs[(wn + i * 16 + frow) * 32 + kg * 8];
#pragma unroll
    for (int i = 0; i < 4; i++)
#pragma unroll
      for (int j = 0; j < 4; j++)
        acc[i][j] = __builtin_amdgcn_mfma_f32_16x16x32_bf16(fa[i], fb[j], acc[i][j], 0, 0, 0);
    __syncthreads();
  }

  const int crow = (lane >> 4) * 4, ccol = lane & 15;
#pragma unroll
  for (int i = 0; i < 4; i++)
#pragma unroll
    for (int j = 0; j < 4; j++)
#pragma unroll
      for (int r = 0; r < 4; r++) {
        int gm = bm + wm + i * 16 + crow + r;
        int gn = bn + wn + j * 16 + ccol;
        int b = gm >> 5, jj = gm & 31;
        if (gn < 1024) {
          int h = gn >> 6, d = gn & 63;
          Kout[((((size_t)b * NH + h) * KRET + jj) << 6) + d] = acc[i][j][r];
        } else {
          int gn2 = gn - 1024;
          int h = gn2 >> 6, d = gn2 & 63;
          Vout[((((size_t)b * NH + h) * KRET + jj) << 6) + d] = acc[i][j][r];
        }
      }
}

// ======== shared 256x256 8-phase GEMM core (T2+T3+T4+T5), K=1024, 4-deep ring ========
#define LDSA(SB) (LDS + (SB) * 8192)
#define LDSB(SB) (LDS + 32768 + (SB) * 8192)
#define STG_A(SB, T)                                  \
  do {                                                \
    const int st_ = (T) < 31 ? (T) : 31;              \
    gload16(aS0 + st_ * 32, LDSA(SB) + ldst0);        \
    gload16(aS1 + st_ * 32, LDSA(SB) + ldst1);        \
  } while (0)
#define STG_B(SB, T)                                  \
  do {                                                \
    const int st_ = (T) < 31 ? (T) : 31;              \
    gload16(bS0 + st_ * 32, LDSB(SB) + ldst0);        \
    gload16(bS1 + st_ * 32, LDSB(SB) + ldst1);        \
  } while (0)
#define GPH(CB, I0, NEWB, STMT, VM)                                            \
  do {                                                                         \
    bf16x8 af[4];                                                              \
    _Pragma("unroll") for (int ii = 0; ii < 4; ii++)                           \
        af[ii] = *(const bf16x8*)(LDSA(CB) + ((wr * 128 + (I0 + ii) * 16 + fr) << 5) + (sA << 3)); \
    if (NEWB) {                                                                \
      _Pragma("unroll") for (int jj = 0; jj < 4; jj++)                         \
          bf[jj] = *(const bf16x8*)(LDSB(CB) + ((wc * 64 + jj * 16 + fr) << 5) + (sA << 3)); \
    }                                                                          \
    STMT;                                                                      \
    __builtin_amdgcn_s_barrier();                                              \
    __builtin_amdgcn_s_setprio(1);                                             \
    _Pragma("unroll") for (int ii = 0; ii < 4; ii++)                           \
        _Pragma("unroll") for (int jj = 0; jj < 4; jj++)                       \
            acc[I0 + ii][jj] = __builtin_amdgcn_mfma_f32_16x16x32_bf16(        \
                af[ii], bf[jj], acc[I0 + ii][jj], 0, 0, 0);                    \
    __builtin_amdgcn_s_setprio(0);                                             \
    if (VM) asm volatile("s_waitcnt vmcnt(4)" ::: "memory");                   \
    __builtin_amdgcn_s_barrier();                                              \
  } while (0)
#define GEMM_KLOOP(Ap, Bp)                                                      \
  const int r0 = tid >> 2, s0 = tid & 3;                                        \
  const int sw0 = s0 ^ ((r0 >> 1) & 3);                                         \
  const int r1 = r0 + 128;                                                      \
  const int sw1 = s0 ^ ((r1 >> 1) & 3);                                         \
  const unsigned short* aS0 = (Ap) + (size_t)(bm + r0) * 1024 + sw0 * 8;        \
  const unsigned short* aS1 = (Ap) + (size_t)(bm + r1) * 1024 + sw1 * 8;        \
  const unsigned short* bS0 = (Bp) + (size_t)(bn + r0) * 1024 + sw0 * 8;        \
  const unsigned short* bS1 = (Bp) + (size_t)(bn + r1) * 1024 + sw1 * 8;        \
  const int ldst0 = wid << 9;                                                   \
  const int ldst1 = 4096 + (wid << 9);                                          \
  const int sA = kg ^ ((fr >> 1) & 3);                                          \
  STG_A(0, 0); STG_B(0, 0);                                                     \
  STG_A(1, 1); STG_B(1, 1);                                                     \
  STG_A(2, 2); STG_B(2, 2);                                                     \
  asm volatile("s_waitcnt vmcnt(4)" ::: "memory");                              \
  __builtin_amdgcn_s_barrier();                                                 \
  _Pragma("unroll 1") for (int it = 0; it < 8; ++it) {                          \
    const int t = it * 4;                                                       \
    GPH(0, 0, 1, STG_A(3, t + 3), 0);                                           \
    GPH(0, 4, 0, STG_B(3, t + 3), 0);                                           \
    GPH(1, 0, 1, STG_A(0, t + 4), 0);                                           \
    GPH(1, 4, 0, STG_B(0, t + 4), 1);                                           \
    GPH(2, 0, 1, STG_A(1, t + 5), 0);                                           \
    GPH(2, 4, 0, STG_B(1, t + 5), 0);                                           \
    GPH(3, 0, 1, STG_A(2, t + 6), 0);                                           \
    GPH(3, 4, 0, STG_B(2, t + 6), 1);                                           \
  }

// ---------------- fused Q-projection GEMM + cross-attention ----------------
// Block (bx,by): t-rows bm..bm+255 (one batch), heads by*4..by*4+3.
// After K-loop, LDS is reused: K/V staged bf16; per-wave Q subtile transposed
// through LDS; QK^T -> softmax -> PV; ctx written to ctxb.
__global__ __launch_bounds__(512, 2) void k_qattn(const unsigned short* __restrict__ A,
                                                  const unsigned short* __restrict__ Bt,
                                                  const float* __restrict__ Kws,
                                                  const float* __restrict__ Vws,
                                                  unsigned short* __restrict__ ctx) {
  __shared__ __align__(16) unsigned short LDS[65536];
  const int tid = threadIdx.x;
  const int wid = tid >> 6, lane = tid & 63;
  const int wr = wid >> 2, wc = wid & 3;
  const int fr = lane & 15, kg = lane >> 4;
  const int bm = blockIdx.x * 256, bn = blockIdx.y * 256;

  f32x4 acc[8][4] = {};
  bf16x8 bf[4];

  GEMM_KLOOP(A, Bt)

  // drain in-flight tail loads before LDS reuse
  asm volatile("s_waitcnt vmcnt(0)" ::: "memory");
  __syncthreads();

  // ---- attention phase ----
  unsigned short* Kl = LDS;            // [4][32][72]
  unsigned short* Vt = LDS + 9216;     // [4][64][40]
  unsigned short* Qs = LDS + 19456;    // [8][16][72]
  unsigned short* Pl = LDS + 28672;    // [8][16][40]
  const int b = bm >> 11;
  const int hbase = blockIdx.y * 4;
  {
    int hq = tid >> 7, rem = tid & 127, doc = rem >> 2, dq = (rem & 3) * 16;
    const float4* kp = (const float4*)(Kws + ((((size_t)b * NH + hbase + hq) * KRET + doc) << 6) + dq);
    float4 k0 = kp[0], k1 = kp[1], k2 = kp[2], k3 = kp[3];
    u16x8 ka, kb2;
    ka[0] = f2bf(k0.x); ka[1] = f2bf(k0.y); ka[2] = f2bf(k0.z); ka[3] = f2bf(k0.w);
    ka[4] = f2bf(k1.x); ka[5] = f2bf(k1.y); ka[6] = f2bf(k1.z); ka[7] = f2bf(k1.w);
    kb2[0] = f2bf(k2.x); kb2[1] = f2bf(k2.y); kb2[2] = f2bf(k2.z); kb2[3] = f2bf(k2.w);
    kb2[4] = f2bf(k3.x); kb2[5] = f2bf(k3.y); kb2[6] = f2bf(k3.z); kb2[7] = f2bf(k3.w);
    *(u16x8*)&Kl[hq * 2304 + doc * 72 + dq] = ka;
    *(u16x8*)&Kl[hq * 2304 + doc * 72 + dq + 8] = kb2;
    const float4* vp = (const float4*)(Vws + ((((size_t)b * NH + hbase + hq) * KRET + doc) << 6) + dq);
    float4 v0 = vp[0], v1 = vp[1], v2 = vp[2], v3 = vp[3];
    float vv[16] = {v0.x, v0.y, v0.z, v0.w, v1.x, v1.y, v1.z, v1.w,
                    v2.x, v2.y, v2.z, v2.w, v3.x, v3.y, v3.z, v3.w};
#pragma unroll
    for (int j = 0; j < 16; j++) Vt[hq * 2560 + (dq + j) * 40 + doc] = f2bf(vv[j]);
  }
  __syncthreads();

  unsigned short* Klh = Kl + wc * 2304;
  unsigned short* Vth = Vt + wc * 2560;
  const bf16x8 kb00 = *(const bf16x8*)&Klh[fr * 72 + kg * 8];
  const bf16x8 kb01 = *(const bf16x8*)&Klh[fr * 72 + 32 + kg * 8];
  const bf16x8 kb10 = *(const bf16x8*)&Klh[(16 + fr) * 72 + kg * 8];
  const bf16x8 kb11 = *(const bf16x8*)&Klh[(16 + fr) * 72 + 32 + kg * 8];
  bf16x8 vbf[4];
#pragma unroll
  for (int dt = 0; dt < 4; dt++)
    vbf[dt] = *(const bf16x8*)&Vth[(dt * 16 + fr) * 40 + kg * 8];
  unsigned short* Qw = Qs + wid * 1152;  // 16*72
  unsigned short* pw = Pl + wid * 640;   // 16*40
  const int h = hbase + wc;

#pragma unroll 1
  for (int i = 0; i < 8; ++i) {
    // transpose Q subtile (C-layout -> A-frag layout) through per-wave LDS
#pragma unroll
    for (int j = 0; j < 4; j++)
#pragma unroll
      for (int r = 0; r < 4; r++)
        Qw[(kg * 4 + r) * 72 + j * 16 + fr] = f2bf(acc[i][j][r]);
    asm volatile("s_waitcnt lgkmcnt(0)" ::: "memory");
    bf16x8 qa0 = *(const bf16x8*)&Qw[fr * 72 + kg * 8];
    bf16x8 qa1 = *(const bf16x8*)&Qw[fr * 72 + 32 + kg * 8];
    f32x4 s0 = {}, s1 = {};
    s0 = __builtin_amdgcn_mfma_f32_16x16x32_bf16(qa0, kb00, s0, 0, 0, 0);
    s0 = __builtin_amdgcn_mfma_f32_16x16x32_bf16(qa1, kb01, s0, 0, 0, 0);
    s1 = __builtin_amdgcn_mfma_f32_16x16x32_bf16(qa0, kb10, s1, 0, 0, 0);
    s1 = __builtin_amdgcn_mfma_f32_16x16x32_bf16(qa1, kb11, s1, 0, 0, 0);
    float a0[4], a1[4], mr[4], e0[4], e1[4], sr[4];
#pragma unroll
    for (int r = 0; r < 4; r++) {
      a0[r] = s0[r] * 0.125f; a1[r] = s1[r] * 0.125f;
      mr[r] = fmaxf(a0[r], a1[r]);
    }
#pragma unroll
    for (int m = 1; m < 16; m <<= 1)
#pragma unroll
      for (int r = 0; r < 4; r++) mr[r] = fmaxf(mr[r], __shfl_xor(mr[r], m));
#pragma unroll
    for (int r = 0; r < 4; r++) {
      e0[r] = __expf(a0[r] - mr[r]); e1[r] = __expf(a1[r] - mr[r]);
      sr[r] = e0[r] + e1[r];
    }
#pragma unroll
    for (int m = 1; m < 16; m <<= 1)
#pragma unroll
      for (int r = 0; r < 4; r++) sr[r] += __shfl_xor(sr[r], m);
#pragma unroll
    for (int r = 0; r < 4; r++) {
      float inv = 1.f / sr[r];
      int tl = kg * 4 + r;
      pw[tl * 40 + fr] = f2bf(e0[r] * inv);
      pw[tl * 40 + 16 + fr] = f2bf(e1[r] * inv);
    }
    asm volatile("s_waitcnt lgkmcnt(0)" ::: "memory");
    bf16x8 pa = *(const bf16x8*)&pw[fr * 40 + kg * 8];
    f32x4 c[4];
#pragma unroll
    for (int dt = 0; dt < 4; dt++) {
      f32x4 z = {};
      c[dt] = __builtin_amdgcn_mfma_f32_16x16x32_bf16(pa, vbf[dt], z, 0, 0, 0);
    }
#pragma unroll
    for (int r = 0; r < 4; r++) {
      int tl = kg * 4 + r;
      unsigned short* crow = ctx + ((size_t)(bm + wr * 128 + i * 16 + tl)) * D_MODEL + h * HD;
#pragma unroll
      for (int dt = 0; dt < 4; dt++)
        crow[dt * 16 + fr] = f2bf(c[dt][r]);
    }
  }
}

// ---------------- O-projection GEMM: out = xres + gate * (ctx @ WoT) ----------------
__global__ __launch_bounds__(512, 2) void k_gemmO(const unsigned short* __restrict__ A,
                                                  const unsigned short* __restrict__ Bt,
                                                  float* __restrict__ out_f,
                                                  const float* __restrict__ xres,
                                                  const float* __restrict__ gatep) {
  __shared__ __align__(16) unsigned short LDS[65536];
  const int tid = threadIdx.x;
  const int wid = tid >> 6, lane = tid & 63;
  const int wr = wid >> 2, wc = wid & 3;
  const int fr = lane & 15, kg = lane >> 4;
  const int bm = blockIdx.x * 256, bn = blockIdx.y * 256;

  f32x4 acc[8][4] = {};
  bf16x8 bf[4];

  GEMM_KLOOP(A, Bt)

  const int crow = kg * 4, ccol = fr;
  float gate = 1.f / (1.f + __expf(-gatep[0]));
#pragma unroll
  for (int i = 0; i < 8; i++)
#pragma unroll
    for (int j = 0; j < 4; j++)
#pragma unroll
      for (int r = 0; r < 4; r++) {
        int gm = bm + wr * 128 + i * 16 + crow + r;
        int gn = bn + wc * 64 + j * 16 + ccol;
        size_t off = (size_t)gm * D_MODEL + gn;
        out_f[off] = xres[off] + gate * acc[i][j][r];
      }
}

extern "C" void kernel_launch(void* const* d_in, const int* in_sizes, int n_in,
                              void* d_out, int out_size, void* d_ws, size_t ws_size,
                              hipStream_t stream) {
  const float* x = (const float*)d_in[0];
  const float* mk = (const float*)d_in[1];
  const float* mv = (const float*)d_in[2];
  const float* Wq = (const float*)d_in[3];
  const float* Wk = (const float*)d_in[4];
  const float* Wv = (const float*)d_in[5];
  const float* Wo = (const float*)d_in[6];
  const float* gatep = (const float*)d_in[7];
  float* out = (float*)d_out;

  char* ws = (char*)d_ws;
  unsigned short* xb   = (unsigned short*)(ws);               // 32MB x bf16
  unsigned short* ctxb = (unsigned short*)(ws + 33554432);    // 32MB ctx bf16
  unsigned short* WqT  = (unsigned short*)(ws + 67108864);    // 2MB
  unsigned short* WkvT = (unsigned short*)(ws + 69206016);    // 4MB (Wk^T then Wv^T)
  unsigned short* WoT  = (unsigned short*)(ws + 73400320);    // 2MB
  float* qn    = (float*)(ws + 75497472);                     // 32KB
  float* sims  = (float*)(ws + 75530240);                     // 4MB (first 2MB doubles as part)
  float* part  = (float*)(ws + 75530240);                     // 2MB, dead after k_qnorm
  int*   idx   = (int*)(ws + 79724544);                       // 1KB
  float* cval  = (float*)(ws + 79725568);                     // 64KB
  int*   cidxb = (int*)(ws + 79791104);                       // 64KB
  float* Kws   = (float*)(ws + 79856640);                     // 1MB (B,H,k,hd)
  float* Vws   = (float*)(ws + 80905216);                     // 1MB

  // 1. fused: x -> bf16 + mean partials  ||  weight transposes
  k_prep<<<dim3(1536), 256, 0, stream>>>(x, xb, part, Wq, Wk, Wv, Wo,
                                         WqT, WkvT, WkvT + 1048576, WoT);
  // 2. finish mean + normalize
  k_qnorm<<<dim3(8), 256, 0, stream>>>(part, qn);
  // 3. cosine sims vs key bank
  k_sims<<<dim3(BANK / 16), 256, 0, stream>>>(mk, qn, sims);
  // 4. two-stage exact top-32 per batch
  k_topk_local<<<dim3(64, 8), 256, 0, stream>>>(sims, cval, cidxb);
  k_topk_merge<<<dim3(8), 256, 0, stream>>>(cval, cidxb, idx);
  // 5. K,V = mv[idx] @ [Wk;Wv]  (gather fused)
  k_kvgemm<<<dim3(2, 16), 256, 0, stream>>>(mv, idx, WkvT, Kws, Vws);
  // 6. fused Q-proj GEMM + attention -> ctxb
  k_qattn<<<dim3(64, 4), 512, 0, stream>>>(xb, WqT, Kws, Vws, ctxb);
  // 7. out = x + sigmoid(gate) * ctx @ Wo
  k_gemmO<<<dim3(64, 4), 512, 0, stream>>>(ctxb, WoT, out, x, gatep);
}

// Round 7
// 405.028 us; speedup vs baseline: 2.5274x; 2.5274x over previous
//
#include <hip/hip_runtime.h>

#define D_MODEL 1024
#define NH 16
#define HD 64
#define KRET 32
#define BANK 131072
#define BB 8
#define TT 2048
#define MTOK 16384
#define EPSN 1e-12f

typedef __attribute__((ext_vector_type(8))) short bf16x8;
typedef __attribute__((ext_vector_type(8))) unsigned short u16x8;
typedef __attribute__((ext_vector_type(4))) float f32x4;

__device__ __forceinline__ unsigned short f2bf(float f) {
  unsigned int u = __float_as_uint(f);
  u += 0x7fffu + ((u >> 16) & 1u);
  return (unsigned short)(u >> 16);
}
__device__ __forceinline__ float bf2f(unsigned short h) {
  return __uint_as_float(((unsigned int)h) << 16);
}

__device__ __forceinline__ void gload16(const void* g, void* l) {
  __builtin_amdgcn_global_load_lds(
      (const __attribute__((address_space(1))) unsigned int*)g,
      (__attribute__((address_space(3))) unsigned int*)l, 16, 0, 0);
}

// ---------------- fused prep: conv_mean (blocks 0..511) + transW (blocks 512..1535) ----------------
__global__ __launch_bounds__(256) void k_prep(const float* __restrict__ x,
                                              unsigned short* __restrict__ xb,
                                              float* __restrict__ part,
                                              const float* W0, const float* W1,
                                              const float* W2, const float* W3,
                                              unsigned short* T0, unsigned short* T1,
                                              unsigned short* T2, unsigned short* T3) {
  __shared__ float tile[64][65];
  int id = blockIdx.x, tid = threadIdx.x;
  if (id < 512) {
    int ch = id & 63, b = id >> 6;
    const float4* xp = (const float4*)(x + ((size_t)b * TT + ch * 32) * D_MODEL);
    ushort4* xo = (ushort4*)(xb + ((size_t)b * TT + ch * 32) * D_MODEL);
    float4 acc = {0.f, 0.f, 0.f, 0.f};
#pragma unroll 4
    for (int t = 0; t < 32; t++) {
      float4 v = xp[t * 256 + tid];
      acc.x += v.x; acc.y += v.y; acc.z += v.z; acc.w += v.w;
      ushort4 o;
      o.x = f2bf(v.x); o.y = f2bf(v.y); o.z = f2bf(v.z); o.w = f2bf(v.w);
      xo[t * 256 + tid] = o;
    }
    ((float4*)part)[((size_t)b * 64 + ch) * 256 + tid] = acc;
  } else {
    int wid = id - 512;
    int nx = wid & 15, ny = (wid >> 4) & 15, nz = wid >> 8;
    const float* W; unsigned short* T;
    switch (nz) {
      case 0: W = W0; T = T0; break;
      case 1: W = W1; T = T1; break;
      case 2: W = W2; T = T2; break;
      default: W = W3; T = T3; break;
    }
    int k0 = ny * 64, n0 = nx * 64;
#pragma unroll
    for (int i = 0; i < 16; i++) {
      int idx = tid + i * 256; int r = idx >> 6, c = idx & 63;
      tile[r][c] = W[(size_t)(k0 + r) * D_MODEL + n0 + c];
    }
    __syncthreads();
#pragma unroll
    for (int i = 0; i < 16; i++) {
      int idx = tid + i * 256; int r = idx >> 6, c = idx & 63;
      T[(size_t)(n0 + r) * D_MODEL + k0 + c] = f2bf(tile[c][r]);
    }
  }
}

// ---------------- finish mean (64 partials) + normalize q ----------------
__global__ __launch_bounds__(256) void k_qnorm(const float* __restrict__ part,
                                               float* __restrict__ qn) {
  int b = blockIdx.x; int tid = threadIdx.x;
  __shared__ float red[4];
  const float4* pp = (const float4*)part + (size_t)b * 64 * 256 + tid;
  float4 a = {0.f, 0.f, 0.f, 0.f};
#pragma unroll 8
  for (int p = 0; p < 64; p++) {
    float4 v = pp[(size_t)p * 256];
    a.x += v.x; a.y += v.y; a.z += v.z; a.w += v.w;
  }
  const float sc = 1.f / (float)TT;
  a.x *= sc; a.y *= sc; a.z *= sc; a.w *= sc;
  float ss = a.x * a.x + a.y * a.y + a.z * a.z + a.w * a.w;
#pragma unroll
  for (int m = 32; m >= 1; m >>= 1) ss += __shfl_xor(ss, m);
  if ((tid & 63) == 0) red[tid >> 6] = ss;
  __syncthreads();
  float tot = red[0] + red[1] + red[2] + red[3];
  float inv = 1.f / fmaxf(sqrtf(tot), EPSN);
  float4 o = {a.x * inv, a.y * inv, a.z * inv, a.w * inv};
  ((float4*)qn)[(size_t)b * 256 + tid] = o;
}

// ---------------- cosine sims: one wave per 4 key rows ----------------
__global__ __launch_bounds__(256) void k_sims(const float* __restrict__ mk,
                                              const float* __restrict__ qn,
                                              float* __restrict__ sims) {
  int wave = threadIdx.x >> 6, lane = threadIdx.x & 63;
  int row0 = (blockIdx.x * 4 + wave) * 4;
  float4 kv[4][4];
#pragma unroll
  for (int r = 0; r < 4; r++) {
    const float4* kr = (const float4*)(mk + (size_t)(row0 + r) * D_MODEL);
#pragma unroll
    for (int i = 0; i < 4; i++) kv[r][i] = kr[lane + 64 * i];
  }
  float ss[4] = {0.f, 0.f, 0.f, 0.f};
#pragma unroll
  for (int r = 0; r < 4; r++)
#pragma unroll
    for (int i = 0; i < 4; i++)
      ss[r] += kv[r][i].x * kv[r][i].x + kv[r][i].y * kv[r][i].y +
               kv[r][i].z * kv[r][i].z + kv[r][i].w * kv[r][i].w;
  float dots[8][4];
#pragma unroll
  for (int b = 0; b < 8; b++)
#pragma unroll
    for (int r = 0; r < 4; r++) dots[b][r] = 0.f;
#pragma unroll
  for (int b = 0; b < 8; b++) {
    const float4* qb = (const float4*)(qn + (size_t)b * D_MODEL);
#pragma unroll
    for (int i = 0; i < 4; i++) {
      float4 q4 = qb[lane + 64 * i];
#pragma unroll
      for (int r = 0; r < 4; r++)
        dots[b][r] += kv[r][i].x * q4.x + kv[r][i].y * q4.y +
                      kv[r][i].z * q4.z + kv[r][i].w * q4.w;
    }
  }
#pragma unroll
  for (int m = 32; m >= 1; m >>= 1) {
#pragma unroll
    for (int r = 0; r < 4; r++) ss[r] += __shfl_xor(ss[r], m);
#pragma unroll
    for (int b = 0; b < 8; b++)
#pragma unroll
      for (int r = 0; r < 4; r++) dots[b][r] += __shfl_xor(dots[b][r], m);
  }
  if (lane == 0) {
#pragma unroll
    for (int r = 0; r < 4; r++) {
      float inv = 1.f / fmaxf(sqrtf(ss[r]), EPSN);
#pragma unroll
      for (int b = 0; b < 8; b++)
        sims[(size_t)b * BANK + row0 + r] = dots[b][r] * inv;
    }
  }
}

// ---------------- two-stage exact top-32 ----------------
__global__ __launch_bounds__(256) void k_topk_local(const float* __restrict__ sims,
                                                    float* __restrict__ cval,
                                                    int* __restrict__ cidx) {
  int b = blockIdx.y, chunk = blockIdx.x;
  int tid = threadIdx.x, wave = tid >> 6, lane = tid & 63;
  const float* sb = sims + (size_t)b * BANK + chunk * 2048;
  float v[8]; int gi[8];
#pragma unroll
  for (int j = 0; j < 8; j++) {
    int loc = j * 256 + tid;
    v[j] = sb[loc];
    gi[j] = chunk * 2048 + loc;
  }
  __shared__ float wv[4]; __shared__ int wi[4];
  __shared__ int bcast;
  for (int it = 0; it < KRET; ++it) {
    float best = -1e30f; int besti = 1 << 30;
#pragma unroll
    for (int j = 0; j < 8; j++)
      if (v[j] > best || (v[j] == best && gi[j] < besti)) { best = v[j]; besti = gi[j]; }
#pragma unroll
    for (int m = 32; m >= 1; m >>= 1) {
      float ov = __shfl_xor(best, m); int oi = __shfl_xor(besti, m);
      if (ov > best || (ov == best && oi < besti)) { best = ov; besti = oi; }
    }
    if (lane == 0) { wv[wave] = best; wi[wave] = besti; }
    __syncthreads();
    if (tid == 0) {
      float fb = wv[0]; int fi = wi[0];
      for (int w = 1; w < 4; w++)
        if (wv[w] > fb || (wv[w] == fb && wi[w] < fi)) { fb = wv[w]; fi = wi[w]; }
      bcast = fi;
      cval[((size_t)b * 64 + chunk) * KRET + it] = fb;
      cidx[((size_t)b * 64 + chunk) * KRET + it] = fi;
    }
    __syncthreads();
    int w = bcast;
#pragma unroll
    for (int j = 0; j < 8; j++)
      if (gi[j] == w) v[j] = -1e30f;
  }
}

__global__ __launch_bounds__(256) void k_topk_merge(const float* __restrict__ cval,
                                                    const int* __restrict__ cidx,
                                                    int* __restrict__ idx) {
  int b = blockIdx.x;
  int tid = threadIdx.x, wave = tid >> 6, lane = tid & 63;
  const float* cv = cval + (size_t)b * 2048;
  const int* ci = cidx + (size_t)b * 2048;
  float v[8]; int gi[8];
#pragma unroll
  for (int j = 0; j < 8; j++) {
    int loc = j * 256 + tid;
    v[j] = cv[loc];
    gi[j] = ci[loc];
  }
  __shared__ float wv[4]; __shared__ int wi[4];
  __shared__ int bcast;
  for (int it = 0; it < KRET; ++it) {
    float best = -1e30f; int besti = 1 << 30;
#pragma unroll
    for (int j = 0; j < 8; j++)
      if (v[j] > best || (v[j] == best && gi[j] < besti)) { best = v[j]; besti = gi[j]; }
#pragma unroll
    for (int m = 32; m >= 1; m >>= 1) {
      float ov = __shfl_xor(best, m); int oi = __shfl_xor(besti, m);
      if (ov > best || (ov == best && oi < besti)) { best = ov; besti = oi; }
    }
    if (lane == 0) { wv[wave] = best; wi[wave] = besti; }
    __syncthreads();
    if (tid == 0) {
      float fb = wv[0]; int fi = wi[0];
      for (int w = 1; w < 4; w++)
        if (wv[w] > fb || (wv[w] == fb && wi[w] < fi)) { fb = wv[w]; fi = wi[w]; }
      bcast = fi;
      idx[b * KRET + it] = fi;
    }
    __syncthreads();
    int w = bcast;
#pragma unroll
    for (int j = 0; j < 8; j++)
      if (gi[j] == w) v[j] = -1e30f;
  }
}

// ---------------- KV projection with fused gather: A rows = mv[idx[.]] ----------------
__global__ __launch_bounds__(256) void k_kvgemm(const float* __restrict__ mv,
                                                const int* __restrict__ idx_g,
                                                const unsigned short* __restrict__ Bt,
                                                float* __restrict__ Kout,
                                                float* __restrict__ Vout) {
  __shared__ __align__(16) unsigned short As[128 * 32];
  __shared__ __align__(16) unsigned short Bs[128 * 32];
  __shared__ int idxs[128];
  const int tid = threadIdx.x;
  const int wave = tid >> 6, lane = tid & 63;
  const int bm = blockIdx.x * 128, bn = blockIdx.y * 128;
  const int wm = (wave >> 1) * 64, wn = (wave & 1) * 64;
  const int frow = lane & 15, kg = lane >> 4;
  const int K = 1024;

  if (tid < 128) idxs[tid] = idx_g[bm + tid];
  __syncthreads();

  f32x4 acc[4][4] = {};

  const int row0 = tid >> 2, col0 = (tid & 3) * 8;
  const int row1 = row0 + 64;
  const int g0 = tid * 8;
  const int g1 = 2048 + tid * 8;
  const unsigned short* b0 = Bt + (size_t)(bn + (g0 >> 5)) * K + (g0 & 31);
  const unsigned short* b1 = Bt + (size_t)(bn + (g1 >> 5)) * K + (g1 & 31);
  unsigned short* lB0 = &Bs[wave * 512];
  unsigned short* lB1 = &Bs[2048 + wave * 512];
  const float* src0 = mv + (size_t)idxs[row0] * D_MODEL + col0;
  const float* src1 = mv + (size_t)idxs[row1] * D_MODEL + col0;

  for (int k0 = 0; k0 < K; k0 += 32) {
    gload16(b0 + k0, lB0);
    gload16(b1 + k0, lB1);
    float4 u0 = *(const float4*)(src0 + k0);
    float4 w0 = *(const float4*)(src0 + k0 + 4);
    float4 u1 = *(const float4*)(src1 + k0);
    float4 w1 = *(const float4*)(src1 + k0 + 4);
    u16x8 p0, p1;
    p0[0] = f2bf(u0.x); p0[1] = f2bf(u0.y); p0[2] = f2bf(u0.z); p0[3] = f2bf(u0.w);
    p0[4] = f2bf(w0.x); p0[5] = f2bf(w0.y); p0[6] = f2bf(w0.z); p0[7] = f2bf(w0.w);
    p1[0] = f2bf(u1.x); p1[1] = f2bf(u1.y); p1[2] = f2bf(u1.z); p1[3] = f2bf(u1.w);
    p1[4] = f2bf(w1.x); p1[5] = f2bf(w1.y); p1[6] = f2bf(w1.z); p1[7] = f2bf(w1.w);
    *(u16x8*)&As[row0 * 32 + col0] = p0;
    *(u16x8*)&As[row1 * 32 + col0] = p1;
    __syncthreads();
    bf16x8 fa[4], fb[4];
#pragma unroll
    for (int i = 0; i < 4; i++)
      fa[i] = *(const bf16x8*)&As[(wm + i * 16 + frow) * 32 + kg * 8];
#pragma unroll
    for (int i = 0; i < 4; i++)
      fb[i] = *(const bf16x8*)&Bs[(wn + i * 16 + frow) * 32 + kg * 8];
#pragma unroll
    for (int i = 0; i < 4; i++)
#pragma unroll
      for (int j = 0; j < 4; j++)
        acc[i][j] = __builtin_amdgcn_mfma_f32_16x16x32_bf16(fa[i], fb[j], acc[i][j], 0, 0, 0);
    __syncthreads();
  }

  const int crow = (lane >> 4) * 4, ccol = lane & 15;
#pragma unroll
  for (int i = 0; i < 4; i++)
#pragma unroll
    for (int j = 0; j < 4; j++)
#pragma unroll
      for (int r = 0; r < 4; r++) {
        int gm = bm + wm + i * 16 + crow + r;
        int gn = bn + wn + j * 16 + ccol;
        int b = gm >> 5, jj = gm & 31;
        if (gn < 1024) {
          int h = gn >> 6, d = gn & 63;
          Kout[((((size_t)b * NH + h) * KRET + jj) << 6) + d] = acc[i][j][r];
        } else {
          int gn2 = gn - 1024;
          int h = gn2 >> 6, d = gn2 & 63;
          Vout[((((size_t)b * NH + h) * KRET + jj) << 6) + d] = acc[i][j][r];
        }
      }
}

// ======== shared 256x256 8-phase GEMM core (T2+T3+T4+T5), K=1024, 4-deep ring ========
#define LDSA(SB) (LDS + (SB) * 8192)
#define LDSB(SB) (LDS + 32768 + (SB) * 8192)
#define STG_A(SB, T)                                  \
  do {                                                \
    const int st_ = (T) < 31 ? (T) : 31;              \
    gload16(aS0 + st_ * 32, LDSA(SB) + ldst0);        \
    gload16(aS1 + st_ * 32, LDSA(SB) + ldst1);        \
  } while (0)
#define STG_B(SB, T)                                  \
  do {                                                \
    const int st_ = (T) < 31 ? (T) : 31;              \
    gload16(bS0 + st_ * 32, LDSB(SB) + ldst0);        \
    gload16(bS1 + st_ * 32, LDSB(SB) + ldst1);        \
  } while (0)
#define GPH(CB, I0, NEWB, STMT, VM)                                            \
  do {                                                                         \
    bf16x8 af[4];                                                              \
    _Pragma("unroll") for (int ii = 0; ii < 4; ii++)                           \
        af[ii] = *(const bf16x8*)(LDSA(CB) + ((wr * 128 + (I0 + ii) * 16 + fr) << 5) + (sA << 3)); \
    if (NEWB) {                                                                \
      _Pragma("unroll") for (int jj = 0; jj < 4; jj++)                         \
          bf[jj] = *(const bf16x8*)(LDSB(CB) + ((wc * 64 + jj * 16 + fr) << 5) + (sA << 3)); \
    }                                                                          \
    STMT;                                                                      \
    __builtin_amdgcn_s_barrier();                                              \
    __builtin_amdgcn_s_setprio(1);                                             \
    _Pragma("unroll") for (int ii = 0; ii < 4; ii++)                           \
        _Pragma("unroll") for (int jj = 0; jj < 4; jj++)                       \
            acc[I0 + ii][jj] = __builtin_amdgcn_mfma_f32_16x16x32_bf16(        \
                af[ii], bf[jj], acc[I0 + ii][jj], 0, 0, 0);                    \
    __builtin_amdgcn_s_setprio(0);                                             \
    if (VM) asm volatile("s_waitcnt vmcnt(4)" ::: "memory");                   \
    __builtin_amdgcn_s_barrier();                                              \
  } while (0)
#define GEMM_KLOOP(Ap, Bp)                                                      \
  const int r0 = tid >> 2, s0 = tid & 3;                                        \
  const int sw0 = s0 ^ ((r0 >> 1) & 3);                                         \
  const int r1 = r0 + 128;                                                      \
  const int sw1 = s0 ^ ((r1 >> 1) & 3);                                         \
  const unsigned short* aS0 = (Ap) + (size_t)(bm + r0) * 1024 + sw0 * 8;        \
  const unsigned short* aS1 = (Ap) + (size_t)(bm + r1) * 1024 + sw1 * 8;        \
  const unsigned short* bS0 = (Bp) + (size_t)(bn + r0) * 1024 + sw0 * 8;        \
  const unsigned short* bS1 = (Bp) + (size_t)(bn + r1) * 1024 + sw1 * 8;        \
  const int ldst0 = wid << 9;                                                   \
  const int ldst1 = 4096 + (wid << 9);                                          \
  const int sA = kg ^ ((fr >> 1) & 3);                                          \
  STG_A(0, 0); STG_B(0, 0);                                                     \
  STG_A(1, 1); STG_B(1, 1);                                                     \
  STG_A(2, 2); STG_B(2, 2);                                                     \
  asm volatile("s_waitcnt vmcnt(4)" ::: "memory");                              \
  __builtin_amdgcn_s_barrier();                                                 \
  _Pragma("unroll 1") for (int it = 0; it < 8; ++it) {                          \
    const int t = it * 4;                                                       \
    GPH(0, 0, 1, STG_A(3, t + 3), 0);                                           \
    GPH(0, 4, 0, STG_B(3, t + 3), 0);                                           \
    GPH(1, 0, 1, STG_A(0, t + 4), 0);                                           \
    GPH(1, 4, 0, STG_B(0, t + 4), 1);                                           \
    GPH(2, 0, 1, STG_A(1, t + 5), 0);                                           \
    GPH(2, 4, 0, STG_B(1, t + 5), 0);                                           \
    GPH(3, 0, 1, STG_A(2, t + 6), 0);                                           \
    GPH(3, 4, 0, STG_B(2, t + 6), 1);                                           \
  }

// ---------------- fused Q-projection GEMM + cross-attention ----------------
// Block (bx,by): t-rows bm..bm+255 (one batch), heads by*4..by*4+3.
// NOTE: attention i-loop MUST be fully unrolled — runtime-indexed acc[i]
// demotes the whole accumulator to scratch (rule #20; R6's 685us bug).
__global__ __launch_bounds__(512, 2) void k_qattn(const unsigned short* __restrict__ A,
                                                  const unsigned short* __restrict__ Bt,
                                                  const float* __restrict__ Kws,
                                                  const float* __restrict__ Vws,
                                                  unsigned short* __restrict__ ctx) {
  __shared__ __align__(16) unsigned short LDS[65536];
  const int tid = threadIdx.x;
  const int wid = tid >> 6, lane = tid & 63;
  const int wr = wid >> 2, wc = wid & 3;
  const int fr = lane & 15, kg = lane >> 4;
  const int bm = blockIdx.x * 256, bn = blockIdx.y * 256;

  f32x4 acc[8][4] = {};
  bf16x8 bf[4];

  GEMM_KLOOP(A, Bt)

  // drain in-flight tail loads before LDS reuse
  asm volatile("s_waitcnt vmcnt(0)" ::: "memory");
  __syncthreads();

  // ---- attention phase ----
  unsigned short* Kl = LDS;            // [4][32][72]
  unsigned short* Vt = LDS + 9216;     // [4][64][40]
  unsigned short* Qs = LDS + 19456;    // [8][16][72]
  unsigned short* Pl = LDS + 28672;    // [8][16][40]
  const int b = bm >> 11;
  const int hbase = blockIdx.y * 4;
  {
    int hq = tid >> 7, rem = tid & 127, doc = rem >> 2, dq = (rem & 3) * 16;
    const float4* kp = (const float4*)(Kws + ((((size_t)b * NH + hbase + hq) * KRET + doc) << 6) + dq);
    float4 k0 = kp[0], k1 = kp[1], k2 = kp[2], k3 = kp[3];
    u16x8 ka, kb2;
    ka[0] = f2bf(k0.x); ka[1] = f2bf(k0.y); ka[2] = f2bf(k0.z); ka[3] = f2bf(k0.w);
    ka[4] = f2bf(k1.x); ka[5] = f2bf(k1.y); ka[6] = f2bf(k1.z); ka[7] = f2bf(k1.w);
    kb2[0] = f2bf(k2.x); kb2[1] = f2bf(k2.y); kb2[2] = f2bf(k2.z); kb2[3] = f2bf(k2.w);
    kb2[4] = f2bf(k3.x); kb2[5] = f2bf(k3.y); kb2[6] = f2bf(k3.z); kb2[7] = f2bf(k3.w);
    *(u16x8*)&Kl[hq * 2304 + doc * 72 + dq] = ka;
    *(u16x8*)&Kl[hq * 2304 + doc * 72 + dq + 8] = kb2;
    const float4* vp = (const float4*)(Vws + ((((size_t)b * NH + hbase + hq) * KRET + doc) << 6) + dq);
    float4 v0 = vp[0], v1 = vp[1], v2 = vp[2], v3 = vp[3];
    float vv[16] = {v0.x, v0.y, v0.z, v0.w, v1.x, v1.y, v1.z, v1.w,
                    v2.x, v2.y, v2.z, v2.w, v3.x, v3.y, v3.z, v3.w};
#pragma unroll
    for (int j = 0; j < 16; j++) Vt[hq * 2560 + (dq + j) * 40 + doc] = f2bf(vv[j]);
  }
  __syncthreads();

  unsigned short* Klh = Kl + wc * 2304;
  unsigned short* Vth = Vt + wc * 2560;
  const bf16x8 kb00 = *(const bf16x8*)&Klh[fr * 72 + kg * 8];
  const bf16x8 kb01 = *(const bf16x8*)&Klh[fr * 72 + 32 + kg * 8];
  const bf16x8 kb10 = *(const bf16x8*)&Klh[(16 + fr) * 72 + kg * 8];
  const bf16x8 kb11 = *(const bf16x8*)&Klh[(16 + fr) * 72 + 32 + kg * 8];
  bf16x8 vbf[4];
#pragma unroll
  for (int dt = 0; dt < 4; dt++)
    vbf[dt] = *(const bf16x8*)&Vth[(dt * 16 + fr) * 40 + kg * 8];
  unsigned short* Qw = Qs + wid * 1152;  // 16*72
  unsigned short* pw = Pl + wid * 640;   // 16*40
  const int h = hbase + wc;

#pragma unroll
  for (int i = 0; i < 8; ++i) {
    // transpose Q subtile (C-layout -> A-frag layout) through per-wave LDS
#pragma unroll
    for (int j = 0; j < 4; j++)
#pragma unroll
      for (int r = 0; r < 4; r++)
        Qw[(kg * 4 + r) * 72 + j * 16 + fr] = f2bf(acc[i][j][r]);
    asm volatile("s_waitcnt lgkmcnt(0)" ::: "memory");
    bf16x8 qa0 = *(const bf16x8*)&Qw[fr * 72 + kg * 8];
    bf16x8 qa1 = *(const bf16x8*)&Qw[fr * 72 + 32 + kg * 8];
    f32x4 s0 = {}, s1 = {};
    s0 = __builtin_amdgcn_mfma_f32_16x16x32_bf16(qa0, kb00, s0, 0, 0, 0);
    s0 = __builtin_amdgcn_mfma_f32_16x16x32_bf16(qa1, kb01, s0, 0, 0, 0);
    s1 = __builtin_amdgcn_mfma_f32_16x16x32_bf16(qa0, kb10, s1, 0, 0, 0);
    s1 = __builtin_amdgcn_mfma_f32_16x16x32_bf16(qa1, kb11, s1, 0, 0, 0);
    float a0[4], a1[4], mr[4], e0[4], e1[4], sr[4];
#pragma unroll
    for (int r = 0; r < 4; r++) {
      a0[r] = s0[r] * 0.125f; a1[r] = s1[r] * 0.125f;
      mr[r] = fmaxf(a0[r], a1[r]);
    }
#pragma unroll
    for (int m = 1; m < 16; m <<= 1)
#pragma unroll
      for (int r = 0; r < 4; r++) mr[r] = fmaxf(mr[r], __shfl_xor(mr[r], m));
#pragma unroll
    for (int r = 0; r < 4; r++) {
      e0[r] = __expf(a0[r] - mr[r]); e1[r] = __expf(a1[r] - mr[r]);
      sr[r] = e0[r] + e1[r];
    }
#pragma unroll
    for (int m = 1; m < 16; m <<= 1)
#pragma unroll
      for (int r = 0; r < 4; r++) sr[r] += __shfl_xor(sr[r], m);
#pragma unroll
    for (int r = 0; r < 4; r++) {
      float inv = 1.f / sr[r];
      int tl = kg * 4 + r;
      pw[tl * 40 + fr] = f2bf(e0[r] * inv);
      pw[tl * 40 + 16 + fr] = f2bf(e1[r] * inv);
    }
    asm volatile("s_waitcnt lgkmcnt(0)" ::: "memory");
    bf16x8 pa = *(const bf16x8*)&pw[fr * 40 + kg * 8];
    f32x4 c[4];
#pragma unroll
    for (int dt = 0; dt < 4; dt++) {
      f32x4 z = {};
      c[dt] = __builtin_amdgcn_mfma_f32_16x16x32_bf16(pa, vbf[dt], z, 0, 0, 0);
    }
#pragma unroll
    for (int r = 0; r < 4; r++) {
      int tl = kg * 4 + r;
      unsigned short* crow = ctx + ((size_t)(bm + wr * 128 + i * 16 + tl)) * D_MODEL + h * HD;
#pragma unroll
      for (int dt = 0; dt < 4; dt++)
        crow[dt * 16 + fr] = f2bf(c[dt][r]);
    }
  }
}

// ---------------- O-projection GEMM: out = xres + gate * (ctx @ WoT) ----------------
__global__ __launch_bounds__(512, 2) void k_gemmO(const unsigned short* __restrict__ A,
                                                  const unsigned short* __restrict__ Bt,
                                                  float* __restrict__ out_f,
                                                  const float* __restrict__ xres,
                                                  const float* __restrict__ gatep) {
  __shared__ __align__(16) unsigned short LDS[65536];
  const int tid = threadIdx.x;
  const int wid = tid >> 6, lane = tid & 63;
  const int wr = wid >> 2, wc = wid & 3;
  const int fr = lane & 15, kg = lane >> 4;
  const int bm = blockIdx.x * 256, bn = blockIdx.y * 256;

  f32x4 acc[8][4] = {};
  bf16x8 bf[4];

  GEMM_KLOOP(A, Bt)

  const int crow = kg * 4, ccol = fr;
  float gate = 1.f / (1.f + __expf(-gatep[0]));
#pragma unroll
  for (int i = 0; i < 8; i++)
#pragma unroll
    for (int j = 0; j < 4; j++)
#pragma unroll
      for (int r = 0; r < 4; r++) {
        int gm = bm + wr * 128 + i * 16 + crow + r;
        int gn = bn + wc * 64 + j * 16 + ccol;
        size_t off = (size_t)gm * D_MODEL + gn;
        out_f[off] = xres[off] + gate * acc[i][j][r];
      }
}

extern "C" void kernel_launch(void* const* d_in, const int* in_sizes, int n_in,
                              void* d_out, int out_size, void* d_ws, size_t ws_size,
                              hipStream_t stream) {
  const float* x = (const float*)d_in[0];
  const float* mk = (const float*)d_in[1];
  const float* mv = (const float*)d_in[2];
  const float* Wq = (const float*)d_in[3];
  const float* Wk = (const float*)d_in[4];
  const float* Wv = (const float*)d_in[5];
  const float* Wo = (const float*)d_in[6];
  const float* gatep = (const float*)d_in[7];
  float* out = (float*)d_out;

  char* ws = (char*)d_ws;
  unsigned short* xb   = (unsigned short*)(ws);               // 32MB x bf16
  unsigned short* ctxb = (unsigned short*)(ws + 33554432);    // 32MB ctx bf16
  unsigned short* WqT  = (unsigned short*)(ws + 67108864);    // 2MB
  unsigned short* WkvT = (unsigned short*)(ws + 69206016);    // 4MB (Wk^T then Wv^T)
  unsigned short* WoT  = (unsigned short*)(ws + 73400320);    // 2MB
  float* qn    = (float*)(ws + 75497472);                     // 32KB
  float* sims  = (float*)(ws + 75530240);                     // 4MB (first 2MB doubles as part)
  float* part  = (float*)(ws + 75530240);                     // 2MB, dead after k_qnorm
  int*   idx   = (int*)(ws + 79724544);                       // 1KB
  float* cval  = (float*)(ws + 79725568);                     // 64KB
  int*   cidxb = (int*)(ws + 79791104);                       // 64KB
  float* Kws   = (float*)(ws + 79856640);                     // 1MB (B,H,k,hd)
  float* Vws   = (float*)(ws + 80905216);                     // 1MB

  // 1. fused: x -> bf16 + mean partials  ||  weight transposes
  k_prep<<<dim3(1536), 256, 0, stream>>>(x, xb, part, Wq, Wk, Wv, Wo,
                                         WqT, WkvT, WkvT + 1048576, WoT);
  // 2. finish mean + normalize
  k_qnorm<<<dim3(8), 256, 0, stream>>>(part, qn);
  // 3. cosine sims vs key bank
  k_sims<<<dim3(BANK / 16), 256, 0, stream>>>(mk, qn, sims);
  // 4. two-stage exact top-32 per batch
  k_topk_local<<<dim3(64, 8), 256, 0, stream>>>(sims, cval, cidxb);
  k_topk_merge<<<dim3(8), 256, 0, stream>>>(cval, cidxb, idx);
  // 5. K,V = mv[idx] @ [Wk;Wv]  (gather fused)
  k_kvgemm<<<dim3(2, 16), 256, 0, stream>>>(mv, idx, WkvT, Kws, Vws);
  // 6. fused Q-proj GEMM + attention -> ctxb
  k_qattn<<<dim3(64, 4), 512, 0, stream>>>(xb, WqT, Kws, Vws, ctxb);
  // 7. out = x + sigmoid(gate) * ctx @ Wo
  k_gemmO<<<dim3(64, 4), 512, 0, stream>>>(ctxb, WoT, out, x, gatep);
}